// Round 10
// baseline (171.043 us; speedup 1.0000x reference)
//
#include <hip/hip_runtime.h>

// B=2, S=2048, E=1024, H=16, D=64.  M = B*S = 4096.
// prep -> GEMM1 (QKV) -> flash attention (KV-split x2 blocks, x2 in-block) -> merge -> GEMM3.

typedef __attribute__((ext_vector_type(8)))  __bf16 bf16x8;
typedef __attribute__((ext_vector_type(4)))  __bf16 bf16x4;
typedef __attribute__((ext_vector_type(2)))  __bf16 bf16x2;
typedef __attribute__((ext_vector_type(4)))  float  f32x4;
typedef __attribute__((ext_vector_type(16))) float  f32x16;
typedef __attribute__((ext_vector_type(2)))  unsigned int u32x2;
typedef __attribute__((ext_vector_type(4)))  unsigned int u32x4;

#define LOG2E 1.4426950408889634f
#define SM_SC (0.125f * LOG2E)   // softmax scale folded with log2(e)

static __device__ __forceinline__ void gl2lds16(const void* g, void* l) {
    __builtin_amdgcn_global_load_lds(
        (__attribute__((address_space(1))) void*)(void*)g,
        (__attribute__((address_space(3))) void*)l, 16, 0, 0);
}

static __device__ __forceinline__ unsigned pku(float a, float b) {
    bf16x2 t = { (__bf16)a, (__bf16)b };
    return __builtin_bit_cast(unsigned, t);
}

// ---------------- prep kernels ----------------
__global__ void prep_x_kern(const float* __restrict__ x, __bf16* __restrict__ xb) {
    int i = (blockIdx.x * 256 + threadIdx.x) * 4;
    f32x4 v = *(const f32x4*)(x + i);
    bf16x4 o = { (__bf16)v[0], (__bf16)v[1], (__bf16)v[2], (__bf16)v[3] };
    *(bf16x4*)(xb + i) = o;
}

// wt[n][k] = W_p[h][k][d] via LDS 64x64 transpose; coalesced both sides.
// grid 768: blk = ((p*16+h)*16)+kt
__global__ void __launch_bounds__(256)
prep_wqkv_kern(const float* __restrict__ Wq, const float* __restrict__ Wk,
               const float* __restrict__ Wv, const float* __restrict__ bq,
               const float* __restrict__ bk, const float* __restrict__ bv,
               __bf16* __restrict__ wt, float* __restrict__ bias) {
    __shared__ float T[64][65];
    const int t = threadIdx.x;
    const int blk = blockIdx.x;
    const int kt = blk & 15, ph = blk >> 4;
    const int h = ph & 15, p = ph >> 4;
    const float* W  = (p == 0) ? Wq : (p == 1) ? Wk : Wv;
    const float* bb = (p == 0) ? bq : (p == 1) ? bk : bv;
    #pragma unroll
    for (int i = 0; i < 4; ++i) {
        int flat = i * 1024 + t * 4;
        int kr = flat >> 6, d4 = flat & 63;
        f32x4 v = *(const f32x4*)(W + (h << 16) + ((kt * 64 + kr) << 6) + d4);
        T[kr][d4] = v[0]; T[kr][d4 + 1] = v[1]; T[kr][d4 + 2] = v[2]; T[kr][d4 + 3] = v[3];
    }
    __syncthreads();
    const int d = t >> 2, kq = (t & 3) << 4;
    bf16x8 o0, o1;
    #pragma unroll
    for (int j = 0; j < 8; ++j) o0[j] = (__bf16)T[kq + j][d];
    #pragma unroll
    for (int j = 0; j < 8; ++j) o1[j] = (__bf16)T[kq + 8 + j][d];
    __bf16* dst = wt + (((size_t)(p * 1024 + h * 64 + d)) << 10) + kt * 64 + kq;
    *(bf16x8*)dst = o0;
    *(bf16x8*)(dst + 8) = o1;
    if (kt == 0 && t < 64) bias[p * 1024 + h * 64 + t] = bb[h * 64 + t];
}

// wt[n][k] = W_o[k][n] via LDS 64x64 transpose. grid 256: blk = ktile*16 + nt
__global__ void __launch_bounds__(256)
prep_wo_kern(const float* __restrict__ Wo, __bf16* __restrict__ wt) {
    __shared__ float T[64][65];
    const int t = threadIdx.x;
    const int nt = blockIdx.x & 15, ktile = blockIdx.x >> 4;
    #pragma unroll
    for (int i = 0; i < 4; ++i) {
        int flat = i * 1024 + t * 4;
        int kr = flat >> 6, n4 = flat & 63;
        f32x4 v = *(const f32x4*)(Wo + ((size_t)(ktile * 64 + kr) << 10) + nt * 64 + n4);
        T[kr][n4] = v[0]; T[kr][n4 + 1] = v[1]; T[kr][n4 + 2] = v[2]; T[kr][n4 + 3] = v[3];
    }
    __syncthreads();
    const int n = t >> 2, kq = (t & 3) << 4;
    bf16x8 o0, o1;
    #pragma unroll
    for (int j = 0; j < 8; ++j) o0[j] = (__bf16)T[kq + j][n];
    #pragma unroll
    for (int j = 0; j < 8; ++j) o1[j] = (__bf16)T[kq + 8 + j][n];
    __bf16* dst = wt + (((size_t)(nt * 64 + n)) << 10) + ktile * 64 + kq;
    *(bf16x8*)dst = o0;
    *(bf16x8*)(dst + 8) = o1;
}

// ---------------- GEMM: C[M][N] = A[M][1024] * Bt[N][1024]^T (+bias) ----------------
template <int EPI>
__global__ void __launch_bounds__(256, 2)
gemm_bt(const __bf16* __restrict__ A, const __bf16* __restrict__ Bt,
        const float* __restrict__ bias,
        __bf16* __restrict__ outq, __bf16* __restrict__ outk, __bf16* __restrict__ outv,
        float* __restrict__ outf)
{
    __shared__ __align__(16) __bf16 As[128 * 64];
    __shared__ __align__(16) __bf16 Bs[128 * 64];
    const int tid = threadIdx.x;
    const int wid = tid >> 6, lane = tid & 63;
    const int r = lane & 15, g = lane >> 4;
    const int m0 = blockIdx.y << 7, n0 = blockIdx.x << 7;
    const int wr = wid >> 1, wc = wid & 1;
    f32x4 acc[4][4] = {};
    for (int k0 = 0; k0 < 1024; k0 += 64) {
        #pragma unroll
        for (int c = 0; c < 4; ++c) {
            int cq = (c * 4 + wid) * 64 + lane;   // 16B chunk index in [0,1024)
            int row = cq >> 3, ci = cq & 7;
            gl2lds16(A  + (((size_t)(m0 + row)) << 10) + k0 + ci * 8, As + (c * 4 + wid) * 512);
            gl2lds16(Bt + (((size_t)(n0 + row)) << 10) + k0 + ci * 8, Bs + (c * 4 + wid) * 512);
        }
        __syncthreads();
        bf16x8 af[2][4], bfr[2][4];
        #pragma unroll
        for (int kh = 0; kh < 2; ++kh)
            #pragma unroll
            for (int i = 0; i < 4; ++i) {
                af[kh][i]  = *(const bf16x8*)&As[(wr * 64 + i * 16 + r) * 64 + kh * 32 + g * 8];
                bfr[kh][i] = *(const bf16x8*)&Bs[(wc * 64 + i * 16 + r) * 64 + kh * 32 + g * 8];
            }
        #pragma unroll
        for (int kh = 0; kh < 2; ++kh)
            #pragma unroll
            for (int mi = 0; mi < 4; ++mi)
                #pragma unroll
                for (int ni = 0; ni < 4; ++ni)
                    acc[mi][ni] = __builtin_amdgcn_mfma_f32_16x16x32_bf16(
                        af[kh][mi], bfr[kh][ni], acc[mi][ni], 0, 0, 0);
        __syncthreads();
    }
    if (EPI == 0) {
        #pragma unroll
        for (int ni = 0; ni < 4; ++ni) {
            int n = n0 + wc * 64 + ni * 16 + r;
            float bv = bias[n];
            int p = n >> 10, rem = n & 1023, h = rem >> 6, d = rem & 63;
            #pragma unroll
            for (int mi = 0; mi < 4; ++mi) {
                int mb = m0 + wr * 64 + mi * 16 + g * 4;
                int b = mb >> 11, s = mb & 2047;
                f32x4 v = acc[mi][ni];
                if (p < 2) {
                    __bf16* dst = (p == 0) ? outq : outk;
                    size_t base = (((size_t)(b * 16 + h)) * 2048 + s) * 64 + d;
                    #pragma unroll
                    for (int j = 0; j < 4; ++j)
                        dst[base + (size_t)j * 64] = (__bf16)(v[j] + bv);
                } else {
                    bf16x4 pk = { (__bf16)(v[0] + bv), (__bf16)(v[1] + bv),
                                  (__bf16)(v[2] + bv), (__bf16)(v[3] + bv) };
                    *(bf16x4*)&outv[(((size_t)(b * 16 + h)) * 64 + d) * 2048 + s] = pk;
                }
            }
        }
    } else {
        #pragma unroll
        for (int ni = 0; ni < 4; ++ni) {
            int n = n0 + wc * 64 + ni * 16 + r;
            float bv = bias[n];
            #pragma unroll
            for (int mi = 0; mi < 4; ++mi) {
                int mb = m0 + wr * 64 + mi * 16 + g * 4;
                f32x4 v = acc[mi][ni];
                #pragma unroll
                for (int j = 0; j < 4; ++j)
                    outf[((size_t)(mb + j) << 10) + n] = v[j] + bv;
            }
        }
    }
}

// ---------------- flash attention (swapped 32x32x16, KV-split x2 blocks + x2 in-block) --------
// grid (16, 32), 512 threads = 8 waves. bx&7 = pair x, bx>>3 = KV half kvh.
// Two 4-wave groups split the half-range even/odd: step s stages tiles {t0, t0+1}
// into buf0/buf1 (threads 0-255 stage buf0 = grp0's tile, 256-511 buf1 = grp1's),
// so prefetch-writes are group-local -> 1 barrier/step. 9 steps/block uniformly.
// Segment end: groups merge (m,l,O) via LDS (OM padded x33); cross-block merge_kern
// combines the kvh halves as before. In-reg P (cvt_pk + permlane32_swap).
__global__ void __launch_bounds__(512, 4)
attn_kern(const __bf16* __restrict__ q, const __bf16* __restrict__ k,
          const __bf16* __restrict__ vT, __bf16* __restrict__ pO0,
          __bf16* __restrict__ pO1, float* __restrict__ ml)
{
    __shared__ __align__(16) char smem_raw[36864];   // K/V tiles; overlaid by OM at merge
    __shared__ float ML[4][64][2];
    typedef __bf16 TileT[64][72];
    TileT* Ks  = (TileT*)smem_raw;                   // Ks[2][64][72]
    TileT* VsT = (TileT*)(smem_raw + 18432);         // VsT[2][64][72]
    float* OM  = (float*)smem_raw;                   // [4][64][33] overlay (padded)

    const int tid = threadIdx.x, lane = tid & 63, w = tid >> 6;
    const int grp = w >> 2, wl = w & 3;
    const int r31 = lane & 31, hi = lane >> 5;
    const int x = blockIdx.x & 7, kvh = blockIdx.x >> 3;
    const int bh = blockIdx.y, b = bh >> 4, h = bh & 15;
    const __bf16* qh  = q  + ((size_t)bh << 17);  // [2048][64]
    const __bf16* khp = k  + ((size_t)bh << 17);
    const __bf16* vhp = vT + ((size_t)bh << 17);  // [64][2048]
    __bf16* pO = kvh ? pO1 : pO0;
    // staging coords: thread stages 2 K-chunks + 2 V-chunks of its tile (tb)
    const int tb = tid >> 8, inner = tid & 255;
    const int srow = inner >> 3, sci = inner & 7;

    for (int seg = 0; seg < 2; ++seg) {
        const int j = (seg == 0) ? (15 - x) : x;  // qblk index
        const int qb0 = j << 7;
        const int wrow0 = qb0 + wl * 32;
        const int mg = wrow0 + r31;               // this lane's q-row
        const int c = j + 1;                      // tiles in this kvh half
        const int tbeg = kvh * c;
        const int S = (c + 1) >> 1;               // steps (2 tiles/step)

        bf16x8 qf[4];
        #pragma unroll
        for (int kk = 0; kk < 4; ++kk)
            qf[kk] = *(const bf16x8*)&qh[(size_t)mg * 64 + kk * 16 + hi * 8];

        f32x16 oacc[2] = {};
        float mrun = -3.0e38f, lrun = 0.f;

        __syncthreads();   // protect previous segment's OM reads before restaging
        {   // prologue: stage step 0's tile pair
            int tg = min(tbeg + tb, 31);
            #pragma unroll
            for (int it = 0; it < 2; ++it) {
                int row = srow + it * 32;
                *(bf16x8*)&Ks [tb][row][sci * 8] = *(const bf16x8*)&khp[(size_t)(tg * 64 + row) * 64 + sci * 8];
                *(bf16x8*)&VsT[tb][row][sci * 8] = *(const bf16x8*)&vhp[(size_t)row * 2048 + tg * 64 + sci * 8];
            }
        }
        __syncthreads();

        for (int s = 0; s < S; ++s) {
            const bool pre = (s + 1 < S);
            bf16x8 nk[2], nv[2];
            if (pre) {   // prefetch next step's pair (group-local buffer tb)
                int tg = min(tbeg + 2 * (s + 1) + tb, 31);
                #pragma unroll
                for (int it = 0; it < 2; ++it) {
                    int row = srow + it * 32;
                    nk[it] = *(const bf16x8*)&khp[(size_t)(tg * 64 + row) * 64 + sci * 8];
                    nv[it] = *(const bf16x8*)&vhp[(size_t)row * 2048 + tg * 64 + sci * 8];
                }
            }
            const int t = tbeg + 2 * s + grp;     // my group's tile
            const int n0 = t << 6;
            if ((2 * s + grp < c) && (n0 <= wrow0 + 31)) {
                // ---- QK^T (swapped): sacc = S^T fragments ----
                f32x16 sacc[2] = {};
                #pragma unroll
                for (int kk = 0; kk < 4; ++kk) {
                    bf16x8 kf0 = *(const bf16x8*)&Ks[grp][r31]     [kk * 16 + hi * 8];
                    bf16x8 kf1 = *(const bf16x8*)&Ks[grp][32 + r31][kk * 16 + hi * 8];
                    sacc[0] = __builtin_amdgcn_mfma_f32_32x32x16_bf16(kf0, qf[kk], sacc[0], 0, 0, 0);
                    sacc[1] = __builtin_amdgcn_mfma_f32_32x32x16_bf16(kf1, qf[kk], sacc[1], 0, 0, 0);
                }
                // ---- causal mask (diagonal-touching tiles only) ----
                if (n0 + 63 > wrow0) {
                    #pragma unroll
                    for (int nf = 0; nf < 2; ++nf)
                        #pragma unroll
                        for (int i = 0; i < 16; ++i) {
                            int n = n0 + nf * 32 + (i & 3) + 8 * (i >> 2) + 4 * hi;
                            if (n > mg) sacc[nf][i] = -3.0e38f;
                        }
                }
                // ---- half-row max tree; __all covers both halves exactly ----
                float mx[16];
                #pragma unroll
                for (int i = 0; i < 16; ++i) mx[i] = fmaxf(sacc[0][i], sacc[1][i]);
                #pragma unroll
                for (int st = 8; st > 0; st >>= 1)
                    #pragma unroll
                    for (int i = 0; i < 8; ++i)
                        if (i < st) mx[i] = fmaxf(mx[i], mx[i + st]);
                float pmh = mx[0];
                if (!__all((pmh - mrun) * SM_SC <= 8.0f)) {
                    float pm = fmaxf(pmh, __shfl_xor(pmh, 32));
                    float mnew = fmaxf(mrun, pm);
                    float fac = exp2f((mrun - mnew) * SM_SC);
                    lrun *= fac;
                    #pragma unroll
                    for (int df = 0; df < 2; ++df)
                        #pragma unroll
                        for (int i = 0; i < 16; ++i) oacc[df][i] *= fac;
                    mrun = mnew;
                }
                // ---- P = exp2 (in registers) ----
                #pragma unroll
                for (int nf = 0; nf < 2; ++nf)
                    #pragma unroll
                    for (int i = 0; i < 16; ++i)
                        sacc[nf][i] = exp2f((sacc[nf][i] - mrun) * SM_SC);
                // ---- l: tree sum + cross-half shuffle ----
                {
                    float smv[16];
                    #pragma unroll
                    for (int i = 0; i < 16; ++i) smv[i] = sacc[0][i] + sacc[1][i];
                    #pragma unroll
                    for (int st = 8; st > 0; st >>= 1)
                        #pragma unroll
                        for (int i = 0; i < 8; ++i)
                            if (i < st) smv[i] += smv[i + st];
                    lrun += smv[0] + __shfl_xor(smv[0], 32);
                }
                // ---- pack + cross-half exchange -> PV B-frags; PV ----
                #pragma unroll
                for (int nf = 0; nf < 2; ++nf) {
                    unsigned pk[8];
                    #pragma unroll
                    for (int jj = 0; jj < 8; ++jj)
                        pk[jj] = pku(sacc[nf][2 * jj], sacc[nf][2 * jj + 1]);
#if __has_builtin(__builtin_amdgcn_permlane32_swap)
                    u32x2 s02 = __builtin_amdgcn_permlane32_swap(pk[0], pk[2], false, false);
                    u32x2 s13 = __builtin_amdgcn_permlane32_swap(pk[1], pk[3], false, false);
                    u32x2 s46 = __builtin_amdgcn_permlane32_swap(pk[4], pk[6], false, false);
                    u32x2 s57 = __builtin_amdgcn_permlane32_swap(pk[5], pk[7], false, false);
                    u32x4 fw0 = { s02[0], s13[0], s02[1], s13[1] };
                    u32x4 fw1 = { s46[0], s57[0], s46[1], s57[1] };
#else
                    unsigned rxa = __shfl_xor(hi ? pk[0] : pk[2], 32);
                    unsigned rxb = __shfl_xor(hi ? pk[1] : pk[3], 32);
                    unsigned rxc = __shfl_xor(hi ? pk[4] : pk[6], 32);
                    unsigned rxd = __shfl_xor(hi ? pk[5] : pk[7], 32);
                    u32x4 fw0 = { hi ? rxa : pk[0], hi ? rxb : pk[1],
                                  hi ? pk[2] : rxa, hi ? pk[3] : rxb };
                    u32x4 fw1 = { hi ? rxc : pk[4], hi ? rxd : pk[5],
                                  hi ? pk[6] : rxc, hi ? pk[7] : rxd };
#endif
                    bf16x8 pf0 = __builtin_bit_cast(bf16x8, fw0);
                    bf16x8 pf1 = __builtin_bit_cast(bf16x8, fw1);
                    #pragma unroll
                    for (int kl = 0; kl < 2; ++kl) {
                        const bf16x8 pf = kl ? pf1 : pf0;
                        const int kk = nf * 2 + kl;
                        bf16x8 af0 = *(const bf16x8*)&VsT[grp][r31]     [kk * 16 + hi * 8];
                        bf16x8 af1 = *(const bf16x8*)&VsT[grp][32 + r31][kk * 16 + hi * 8];
                        oacc[0] = __builtin_amdgcn_mfma_f32_32x32x16_bf16(af0, pf, oacc[0], 0, 0, 0);
                        oacc[1] = __builtin_amdgcn_mfma_f32_32x32x16_bf16(af1, pf, oacc[1], 0, 0, 0);
                    }
                }
            }
            if (pre) {   // write prefetched pair into group-local buffer
                #pragma unroll
                for (int it = 0; it < 2; ++it) {
                    int row = srow + it * 32;
                    *(bf16x8*)&Ks [tb][row][sci * 8] = nk[it];
                    *(bf16x8*)&VsT[tb][row][sci * 8] = nv[it];
                }
            }
            __syncthreads();                      // one barrier per step
        }
        // ---- in-block merge of the two groups, then epilogue by grp1 ----
        if (grp == 0) {
            float* dst = OM + (wl * 64 + lane) * 33;
            #pragma unroll
            for (int df = 0; df < 2; ++df)
                #pragma unroll
                for (int i = 0; i < 16; ++i) dst[df * 16 + i] = oacc[df][i];
            ML[wl][lane][0] = mrun;
            ML[wl][lane][1] = lrun;
        }
        __syncthreads();
        if (grp == 1) {
            const float* src = OM + (wl * 64 + lane) * 33;
            float mA = ML[wl][lane][0], lA = ML[wl][lane][1];
            float ms = fmaxf(mA, mrun);
            float wA = exp2f((mA - ms) * SM_SC);
            float wB = exp2f((mrun - ms) * SM_SC);
            float lC = wA * lA + wB * lrun;
            float inv = (lC > 0.f) ? 1.0f / lC : 0.f;
            #pragma unroll
            for (int df = 0; df < 2; ++df)
                #pragma unroll
                for (int td = 0; td < 8; ++td) {
                    float a0 = wA * src[df * 16 + 2 * td]     + wB * oacc[df][2 * td];
                    float a1 = wA * src[df * 16 + 2 * td + 1] + wB * oacc[df][2 * td + 1];
                    bf16x2 pr = { (__bf16)(a0 * inv), (__bf16)(a1 * inv) };
                    int d = df * 32 + 8 * (td >> 1) + 4 * hi + 2 * (td & 1);
                    *(bf16x2*)&pO[((size_t)(b * 2048 + mg) << 10) + h * 64 + d] = pr;
                }
            if (hi == 0) {
                size_t mi = (((size_t)kvh * 32 + bh) * 2048 + mg) * 2;
                ml[mi] = ms;
                ml[mi + 1] = lC;
            }
        }
    }
}

// ---------------- merge: ob = w0*pO0 + w1*ob ----------------
__global__ void merge_kern(const __bf16* __restrict__ pO0, const float* __restrict__ ml,
                           __bf16* __restrict__ ob)
{
    int i = blockIdx.x * 256 + threadIdx.x;       // 1,048,576 threads, 8 elems each
    int m = i >> 7, rem = i & 127, h = rem >> 3, d8 = (rem & 7) * 8;
    int bh = (m >> 11) * 16 + h, sr = m & 2047;
    size_t i0 = ((size_t)bh * 2048 + sr) * 2;
    float m0 = ml[i0], l0 = ml[i0 + 1];
    float m1 = ml[131072 + i0], l1 = ml[131072 + i0 + 1];
    float mx = fmaxf(m0, m1);
    float c0 = exp2f((m0 - mx) * SM_SC) * l0;
    float c1 = exp2f((m1 - mx) * SM_SC) * l1;
    float inv = 1.0f / (c0 + c1);                 // l0 > 0 always
    float w0 = c0 * inv, w1 = c1 * inv;
    size_t off = (size_t)m * 1024 + h * 64 + d8;
    bf16x8 a = *(const bf16x8*)(pO0 + off);
    bf16x8 c = *(const bf16x8*)(ob + off);
    bf16x8 r;
    #pragma unroll
    for (int j = 0; j < 8; ++j) r[j] = (__bf16)(w0 * (float)a[j] + w1 * (float)c[j]);
    *(bf16x8*)(ob + off) = r;
}

// ---------------- launch ----------------
extern "C" void kernel_launch(void* const* d_in, const int* in_sizes, int n_in,
                              void* d_out, int out_size, void* d_ws, size_t ws_size,
                              hipStream_t stream) {
    const float* x  = (const float*)d_in[0];
    const float* Wq = (const float*)d_in[1];
    const float* bq = (const float*)d_in[2];
    const float* Wk = (const float*)d_in[3];
    const float* bk = (const float*)d_in[4];
    const float* Wv = (const float*)d_in[5];
    const float* bv = (const float*)d_in[6];
    const float* Wo = (const float*)d_in[7];
    const float* bo = (const float*)d_in[8];
    float* out = (float*)d_out;
    char* ws = (char*)d_ws;
    // workspace layout (bytes), total ~50 MB; xb/wtqkv regions reused after GEMM1
    __bf16* xb    = (__bf16*)(ws + 0);          //  8 MB  x bf16 [4096][1024]; later pO0
    __bf16* wtqkv = (__bf16*)(ws + 8388608);    //  6 MB  qkv weights^T; later ml (2 MB)
    __bf16* wot   = (__bf16*)(ws + 14680064);   //  2 MB  W_o^T [1024][1024]
    float*  biasq = (float*) (ws + 16777216);   // 12 KB  fused qkv bias
    __bf16* qb    = (__bf16*)(ws + 16793600);   //  8 MB  q [32][2048][64]
    __bf16* kb    = (__bf16*)(ws + 25182208);   //  8 MB  k [32][2048][64]
    __bf16* vtb   = (__bf16*)(ws + 33570816);   //  8 MB  v^T [32][64][2048]
    __bf16* ob    = (__bf16*)(ws + 41959424);   //  8 MB  attn out [4096][1024]
    __bf16* pO0   = xb;                         //  8 MB  partial O (KV half 0)
    float*  mlbuf = (float*)(ws + 8388608);     //  2 MB  (m,l) per [half][bh][row]

    prep_x_kern<<<4096, 256, 0, stream>>>(x, xb);
    prep_wqkv_kern<<<768, 256, 0, stream>>>(Wq, Wk, Wv, bq, bk, bv, wtqkv, biasq);
    prep_wo_kern<<<256, 256, 0, stream>>>(Wo, wot);
    gemm_bt<0><<<dim3(24, 32), 256, 0, stream>>>(xb, wtqkv, biasq, qb, kb, vtb, nullptr);
    attn_kern<<<dim3(16, 32), 512, 0, stream>>>(qb, kb, vtb, pO0, ob, mlbuf);
    merge_kern<<<4096, 256, 0, stream>>>(pO0, mlbuf, ob);
    gemm_bt<1><<<dim3(8, 32), 256, 0, stream>>>(ob, wot, bo, nullptr, nullptr, nullptr, out);
}

// Round 11
// 130.518 us; speedup vs baseline: 1.3105x; 1.3105x over previous
//
#include <hip/hip_runtime.h>

// B=2, S=2048, E=1024, H=16, D=64.  M = B*S = 4096.
// prep -> GEMM1 (QKV) -> flash attention (KV-split x2, partials) -> merge -> GEMM3.

typedef __attribute__((ext_vector_type(8)))  __bf16 bf16x8;
typedef __attribute__((ext_vector_type(4)))  __bf16 bf16x4;
typedef __attribute__((ext_vector_type(2)))  __bf16 bf16x2;
typedef __attribute__((ext_vector_type(4)))  float  f32x4;
typedef __attribute__((ext_vector_type(16))) float  f32x16;
typedef __attribute__((ext_vector_type(2)))  unsigned int u32x2;
typedef __attribute__((ext_vector_type(4)))  unsigned int u32x4;

#define LOG2E 1.4426950408889634f
#define SM_SC (0.125f * LOG2E)   // softmax scale folded with log2(e)

static __device__ __forceinline__ void gl2lds16(const void* g, void* l) {
    __builtin_amdgcn_global_load_lds(
        (__attribute__((address_space(1))) void*)(void*)g,
        (__attribute__((address_space(3))) void*)l, 16, 0, 0);
}

static __device__ __forceinline__ unsigned pku(float a, float b) {
    bf16x2 t = { (__bf16)a, (__bf16)b };
    return __builtin_bit_cast(unsigned, t);
}

// ---------------- prep kernels ----------------
__global__ void prep_x_kern(const float* __restrict__ x, __bf16* __restrict__ xb) {
    int i = (blockIdx.x * 256 + threadIdx.x) * 4;
    f32x4 v = *(const f32x4*)(x + i);
    bf16x4 o = { (__bf16)v[0], (__bf16)v[1], (__bf16)v[2], (__bf16)v[3] };
    *(bf16x4*)(xb + i) = o;
}

// Combined weight prep (one launch):
//  blk < 768 : wt_qkv[n][k] = W_p[h][k][d]  (n = p*1024 + h*64 + d) + bias
//  blk >= 768: wt_o[n][k] = W_o[k][n]
// Both via LDS 64x64 f32 transpose; coalesced on both sides.
__global__ void __launch_bounds__(256)
prep_w_kern(const float* __restrict__ Wq, const float* __restrict__ Wk,
            const float* __restrict__ Wv, const float* __restrict__ bq,
            const float* __restrict__ bk, const float* __restrict__ bv,
            const float* __restrict__ Wo,
            __bf16* __restrict__ wt, float* __restrict__ bias,
            __bf16* __restrict__ wto) {
    __shared__ float T[64][65];
    const int t = threadIdx.x;
    if ((int)blockIdx.x < 768) {
        const int blk = blockIdx.x;
        const int kt = blk & 15, ph = blk >> 4;
        const int h = ph & 15, p = ph >> 4;
        const float* W  = (p == 0) ? Wq : (p == 1) ? Wk : Wv;
        const float* bb = (p == 0) ? bq : (p == 1) ? bk : bv;
        #pragma unroll
        for (int i = 0; i < 4; ++i) {
            int flat = i * 1024 + t * 4;
            int kr = flat >> 6, d4 = flat & 63;
            f32x4 v = *(const f32x4*)(W + (h << 16) + ((kt * 64 + kr) << 6) + d4);
            T[kr][d4] = v[0]; T[kr][d4 + 1] = v[1]; T[kr][d4 + 2] = v[2]; T[kr][d4 + 3] = v[3];
        }
        __syncthreads();
        const int d = t >> 2, kq = (t & 3) << 4;
        bf16x8 o0, o1;
        #pragma unroll
        for (int j = 0; j < 8; ++j) o0[j] = (__bf16)T[kq + j][d];
        #pragma unroll
        for (int j = 0; j < 8; ++j) o1[j] = (__bf16)T[kq + 8 + j][d];
        __bf16* dst = wt + (((size_t)(p * 1024 + h * 64 + d)) << 10) + kt * 64 + kq;
        *(bf16x8*)dst = o0;
        *(bf16x8*)(dst + 8) = o1;
        if (kt == 0 && t < 64) bias[p * 1024 + h * 64 + t] = bb[h * 64 + t];
    } else {
        const int blk = blockIdx.x - 768;
        const int nt = blk & 15, ktile = blk >> 4;
        #pragma unroll
        for (int i = 0; i < 4; ++i) {
            int flat = i * 1024 + t * 4;
            int kr = flat >> 6, n4 = flat & 63;
            f32x4 v = *(const f32x4*)(Wo + ((size_t)(ktile * 64 + kr) << 10) + nt * 64 + n4);
            T[kr][n4] = v[0]; T[kr][n4 + 1] = v[1]; T[kr][n4 + 2] = v[2]; T[kr][n4 + 3] = v[3];
        }
        __syncthreads();
        const int n = t >> 2, kq = (t & 3) << 4;
        bf16x8 o0, o1;
        #pragma unroll
        for (int j = 0; j < 8; ++j) o0[j] = (__bf16)T[kq + j][n];
        #pragma unroll
        for (int j = 0; j < 8; ++j) o1[j] = (__bf16)T[kq + 8 + j][n];
        __bf16* dst = wto + (((size_t)(nt * 64 + n)) << 10) + ktile * 64 + kq;
        *(bf16x8*)dst = o0;
        *(bf16x8*)(dst + 8) = o1;
    }
}

// ---------------- GEMM: C[M][N] = A[M][1024] * Bt[N][1024]^T (+bias) ----------------
template <int EPI>
__global__ void __launch_bounds__(256, 2)
gemm_bt(const __bf16* __restrict__ A, const __bf16* __restrict__ Bt,
        const float* __restrict__ bias,
        __bf16* __restrict__ outq, __bf16* __restrict__ outk, __bf16* __restrict__ outv,
        float* __restrict__ outf)
{
    __shared__ __align__(16) __bf16 As[128 * 64];
    __shared__ __align__(16) __bf16 Bs[128 * 64];
    const int tid = threadIdx.x;
    const int wid = tid >> 6, lane = tid & 63;
    const int r = lane & 15, g = lane >> 4;
    const int m0 = blockIdx.y << 7, n0 = blockIdx.x << 7;
    const int wr = wid >> 1, wc = wid & 1;
    f32x4 acc[4][4] = {};
    for (int k0 = 0; k0 < 1024; k0 += 64) {
        #pragma unroll
        for (int c = 0; c < 4; ++c) {
            int cq = (c * 4 + wid) * 64 + lane;   // 16B chunk index in [0,1024)
            int row = cq >> 3, ci = cq & 7;
            gl2lds16(A  + (((size_t)(m0 + row)) << 10) + k0 + ci * 8, As + (c * 4 + wid) * 512);
            gl2lds16(Bt + (((size_t)(n0 + row)) << 10) + k0 + ci * 8, Bs + (c * 4 + wid) * 512);
        }
        __syncthreads();
        bf16x8 af[2][4], bfr[2][4];
        #pragma unroll
        for (int kh = 0; kh < 2; ++kh)
            #pragma unroll
            for (int i = 0; i < 4; ++i) {
                af[kh][i]  = *(const bf16x8*)&As[(wr * 64 + i * 16 + r) * 64 + kh * 32 + g * 8];
                bfr[kh][i] = *(const bf16x8*)&Bs[(wc * 64 + i * 16 + r) * 64 + kh * 32 + g * 8];
            }
        #pragma unroll
        for (int kh = 0; kh < 2; ++kh)
            #pragma unroll
            for (int mi = 0; mi < 4; ++mi)
                #pragma unroll
                for (int ni = 0; ni < 4; ++ni)
                    acc[mi][ni] = __builtin_amdgcn_mfma_f32_16x16x32_bf16(
                        af[kh][mi], bfr[kh][ni], acc[mi][ni], 0, 0, 0);
        __syncthreads();
    }
    if (EPI == 0) {
        #pragma unroll
        for (int ni = 0; ni < 4; ++ni) {
            int n = n0 + wc * 64 + ni * 16 + r;
            float bv = bias[n];
            int p = n >> 10, rem = n & 1023, h = rem >> 6, d = rem & 63;
            #pragma unroll
            for (int mi = 0; mi < 4; ++mi) {
                int mb = m0 + wr * 64 + mi * 16 + g * 4;
                int b = mb >> 11, s = mb & 2047;
                f32x4 v = acc[mi][ni];
                if (p < 2) {
                    __bf16* dst = (p == 0) ? outq : outk;
                    size_t base = (((size_t)(b * 16 + h)) * 2048 + s) * 64 + d;
                    #pragma unroll
                    for (int j = 0; j < 4; ++j)
                        dst[base + (size_t)j * 64] = (__bf16)(v[j] + bv);
                } else {
                    bf16x4 pk = { (__bf16)(v[0] + bv), (__bf16)(v[1] + bv),
                                  (__bf16)(v[2] + bv), (__bf16)(v[3] + bv) };
                    *(bf16x4*)&outv[(((size_t)(b * 16 + h)) * 64 + d) * 2048 + s] = pk;
                }
            }
        }
    } else {
        #pragma unroll
        for (int ni = 0; ni < 4; ++ni) {
            int n = n0 + wc * 64 + ni * 16 + r;
            float bv = bias[n];
            #pragma unroll
            for (int mi = 0; mi < 4; ++mi) {
                int mb = m0 + wr * 64 + mi * 16 + g * 4;
                f32x4 v = acc[mi][ni];
                #pragma unroll
                for (int j = 0; j < 4; ++j)
                    outf[((size_t)(mb + j) << 10) + n] = v[j] + bv;
            }
        }
    }
}

// ---------------- flash attention (swapped 32x32x16, KV-split x2, in-reg P) ----------------
// R8 structure (proven 50.3 us) + T5 setprio around MFMA clusters.
// grid (16, 32): bx&7 = pair index x, bx>>3 = KV half. P never touches LDS.
// launch_bounds(256,3): VGPR cap 168 -- (256,4)/(512,4) cap 128 < live set (~150)
// and spilled 31-146 MB/dispatch to scratch (R7/R9). 3 blocks/CU allowed, no spill.
__global__ void __launch_bounds__(256, 3)
attn_kern(const __bf16* __restrict__ q, const __bf16* __restrict__ k,
          const __bf16* __restrict__ vT, __bf16* __restrict__ pO0,
          __bf16* __restrict__ pO1, float* __restrict__ ml)
{
    __shared__ __align__(16) __bf16 Ks [2][64][72];
    __shared__ __align__(16) __bf16 VsT[2][64][72];
    const int tid = threadIdx.x, lane = tid & 63, w = tid >> 6;
    const int r31 = lane & 31, hi = lane >> 5;
    const int x = blockIdx.x & 7, kvh = blockIdx.x >> 3;
    const int bh = blockIdx.y, b = bh >> 4, h = bh & 15;
    const __bf16* qh  = q  + ((size_t)bh << 17);  // [2048][64]
    const __bf16* khp = k  + ((size_t)bh << 17);
    const __bf16* vhp = vT + ((size_t)bh << 17);  // [64][2048]
    __bf16* pO = kvh ? pO1 : pO0;
    const int srow = tid >> 3, sci = tid & 7;     // staging: 2 rounds x 32 rows

    for (int seg = 0; seg < 2; ++seg) {
        const int xq = (seg == 0) ? (15 - x) : x; // qblk index j
        const int qb0 = xq << 7;
        const int wrow0 = qb0 + w * 32;
        const int mg = wrow0 + r31;               // this lane's q-row
        const int tbeg = kvh * (xq + 1), tend = tbeg + (xq + 1);

        bf16x8 qf[4];
        #pragma unroll
        for (int kk = 0; kk < 4; ++kk)
            qf[kk] = *(const bf16x8*)&qh[(size_t)mg * 64 + kk * 16 + hi * 8];

        f32x16 oacc[2] = {};
        f32x16 lacc = {};                          // l-sum accumulator (reg0 authoritative)
        float mrun = -3.0e38f;
        bf16x8 onesf;
        #pragma unroll
        for (int j = 0; j < 8; ++j) onesf[j] = (__bf16)1.0f;

        // stage first tile of this range into buffer 0
        #pragma unroll
        for (int it = 0; it < 2; ++it) {
            int row = srow + it * 32;
            *(bf16x8*)&Ks [0][row][sci * 8] = *(const bf16x8*)&khp[(size_t)(tbeg * 64 + row) * 64 + sci * 8];
            *(bf16x8*)&VsT[0][row][sci * 8] = *(const bf16x8*)&vhp[(size_t)row * 2048 + tbeg * 64 + sci * 8];
        }
        __syncthreads();

        for (int t = tbeg; t < tend; ++t) {
            const int cur = (t - tbeg) & 1, nxt = cur ^ 1;
            const int n0 = t << 6;
            const bool pre = (t + 1 < tend);
            bf16x8 nk[2], nv[2];
            if (pre) {   // issue next tile's loads; consumed after compute
                int n1 = n0 + 64;
                #pragma unroll
                for (int it = 0; it < 2; ++it) {
                    int row = srow + it * 32;
                    nk[it] = *(const bf16x8*)&khp[(size_t)(n1 + row) * 64 + sci * 8];
                    nv[it] = *(const bf16x8*)&vhp[(size_t)row * 2048 + n1 + sci * 8];
                }
            }
            if (n0 <= wrow0 + 31) {               // wave-uniform activity guard
                // ---- QK^T (swapped): sacc = S^T fragments ----
                f32x16 sacc[2] = {};
                __builtin_amdgcn_s_setprio(1);
                #pragma unroll
                for (int kk = 0; kk < 4; ++kk) {
                    bf16x8 kf0 = *(const bf16x8*)&Ks[cur][r31]     [kk * 16 + hi * 8];
                    bf16x8 kf1 = *(const bf16x8*)&Ks[cur][32 + r31][kk * 16 + hi * 8];
                    sacc[0] = __builtin_amdgcn_mfma_f32_32x32x16_bf16(kf0, qf[kk], sacc[0], 0, 0, 0);
                    sacc[1] = __builtin_amdgcn_mfma_f32_32x32x16_bf16(kf1, qf[kk], sacc[1], 0, 0, 0);
                }
                __builtin_amdgcn_s_setprio(0);
                // ---- causal mask (diagonal-touching tiles only) ----
                if (n0 + 63 > wrow0) {
                    #pragma unroll
                    for (int nf = 0; nf < 2; ++nf)
                        #pragma unroll
                        for (int i = 0; i < 16; ++i) {
                            int n = n0 + nf * 32 + (i & 3) + 8 * (i >> 2) + 4 * hi;
                            if (n > mg) sacc[nf][i] = -3.0e38f;
                        }
                }
                // ---- half-row max: tree reduce (no cross-half shuffle needed) ----
                float mx[16];
                #pragma unroll
                for (int i = 0; i < 16; ++i) mx[i] = fmaxf(sacc[0][i], sacc[1][i]);
                #pragma unroll
                for (int s = 8; s > 0; s >>= 1)
                    #pragma unroll
                    for (int i = 0; i < 8; ++i)
                        if (i < s) mx[i] = fmaxf(mx[i], mx[i + s]);
                float pmh = mx[0];
                // __all over 64 lanes covers both halves of every row -> exact check
                if (!__all((pmh - mrun) * SM_SC <= 8.0f)) {
                    float pm = fmaxf(pmh, __shfl_xor(pmh, 32));
                    float mnew = fmaxf(mrun, pm);
                    float fac = exp2f((mrun - mnew) * SM_SC);
                    lacc[0] *= fac;               // only reg0 is ever read
                    #pragma unroll
                    for (int df = 0; df < 2; ++df)
                        #pragma unroll
                        for (int i = 0; i < 16; ++i) oacc[df][i] *= fac;
                    mrun = mnew;
                }
                // ---- P = exp2 (stays in registers) ----
                #pragma unroll
                for (int nf = 0; nf < 2; ++nf)
                    #pragma unroll
                    for (int i = 0; i < 16; ++i)
                        sacc[nf][i] = exp2f((sacc[nf][i] - mrun) * SM_SC);
                // ---- pack + cross-half exchange -> PV B-frags; PV + l-sum ----
                #pragma unroll
                for (int nf = 0; nf < 2; ++nf) {
                    unsigned pk[8];
                    #pragma unroll
                    for (int j = 0; j < 8; ++j)
                        pk[j] = pku(sacc[nf][2 * j], sacc[nf][2 * j + 1]);
#if __has_builtin(__builtin_amdgcn_permlane32_swap)
                    u32x2 s02 = __builtin_amdgcn_permlane32_swap(pk[0], pk[2], false, false);
                    u32x2 s13 = __builtin_amdgcn_permlane32_swap(pk[1], pk[3], false, false);
                    u32x2 s46 = __builtin_amdgcn_permlane32_swap(pk[4], pk[6], false, false);
                    u32x2 s57 = __builtin_amdgcn_permlane32_swap(pk[5], pk[7], false, false);
                    u32x4 fw0 = { s02[0], s13[0], s02[1], s13[1] };
                    u32x4 fw1 = { s46[0], s57[0], s46[1], s57[1] };
#else
                    unsigned rxa = __shfl_xor(hi ? pk[0] : pk[2], 32);
                    unsigned rxb = __shfl_xor(hi ? pk[1] : pk[3], 32);
                    unsigned rxc = __shfl_xor(hi ? pk[4] : pk[6], 32);
                    unsigned rxd = __shfl_xor(hi ? pk[5] : pk[7], 32);
                    u32x4 fw0 = { hi ? rxa : pk[0], hi ? rxb : pk[1],
                                  hi ? pk[2] : rxa, hi ? pk[3] : rxb };
                    u32x4 fw1 = { hi ? rxc : pk[4], hi ? rxd : pk[5],
                                  hi ? pk[6] : rxc, hi ? pk[7] : rxd };
#endif
                    bf16x8 pf0 = __builtin_bit_cast(bf16x8, fw0);
                    bf16x8 pf1 = __builtin_bit_cast(bf16x8, fw1);
                    __builtin_amdgcn_s_setprio(1);
                    #pragma unroll
                    for (int kl = 0; kl < 2; ++kl) {
                        const bf16x8 pf = kl ? pf1 : pf0;
                        const int kk = nf * 2 + kl;
                        bf16x8 af0 = *(const bf16x8*)&VsT[cur][r31]     [kk * 16 + hi * 8];
                        bf16x8 af1 = *(const bf16x8*)&VsT[cur][32 + r31][kk * 16 + hi * 8];
                        oacc[0] = __builtin_amdgcn_mfma_f32_32x32x16_bf16(af0, pf, oacc[0], 0, 0, 0);
                        oacc[1] = __builtin_amdgcn_mfma_f32_32x32x16_bf16(af1, pf, oacc[1], 0, 0, 0);
                        lacc    = __builtin_amdgcn_mfma_f32_32x32x16_bf16(onesf, pf, lacc, 0, 0, 0);
                    }
                    __builtin_amdgcn_s_setprio(0);
                }
            }
            if (pre) {   // write prefetched tile into the other buffer
                #pragma unroll
                for (int it = 0; it < 2; ++it) {
                    int row = srow + it * 32;
                    *(bf16x8*)&Ks [nxt][row][sci * 8] = nk[it];
                    *(bf16x8*)&VsT[nxt][row][sci * 8] = nv[it];
                }
            }
            __syncthreads();                      // single barrier per tile
        }
        // ---- epilogue: l-normalized partial O^T + (m,l) ----
        float lrun = lacc[0];
        float inv = (lrun > 0.f) ? 1.0f / lrun : 0.f;
        #pragma unroll
        for (int df = 0; df < 2; ++df)
            #pragma unroll
            for (int td = 0; td < 8; ++td) {
                bf16x2 pr = { (__bf16)(oacc[df][2 * td] * inv),
                              (__bf16)(oacc[df][2 * td + 1] * inv) };
                int d = df * 32 + 8 * (td >> 1) + 4 * hi + 2 * (td & 1);
                *(bf16x2*)&pO[((size_t)(b * 2048 + mg) << 10) + h * 64 + d] = pr;
            }
        if (hi == 0) {
            size_t mi = (((size_t)kvh * 32 + bh) * 2048 + mg) * 2;
            ml[mi] = mrun;
            ml[mi + 1] = lrun;
        }
    }
}

// ---------------- merge: ob = w0*pO0 + w1*ob ----------------
__global__ void merge_kern(const __bf16* __restrict__ pO0, const float* __restrict__ ml,
                           __bf16* __restrict__ ob)
{
    int i = blockIdx.x * 256 + threadIdx.x;       // 1,048,576 threads, 8 elems each
    int m = i >> 7, rem = i & 127, h = rem >> 3, d8 = (rem & 7) * 8;
    int bh = (m >> 11) * 16 + h, sr = m & 2047;
    size_t i0 = ((size_t)bh * 2048 + sr) * 2;
    float m0 = ml[i0], l0 = ml[i0 + 1];
    float m1 = ml[131072 + i0], l1 = ml[131072 + i0 + 1];
    float mx = fmaxf(m0, m1);
    float c0 = exp2f((m0 - mx) * SM_SC) * l0;
    float c1 = exp2f((m1 - mx) * SM_SC) * l1;
    float inv = 1.0f / (c0 + c1);                 // l0 > 0 always
    float w0 = c0 * inv, w1 = c1 * inv;
    size_t off = (size_t)m * 1024 + h * 64 + d8;
    bf16x8 a = *(const bf16x8*)(pO0 + off);
    bf16x8 c = *(const bf16x8*)(ob + off);
    bf16x8 r;
    #pragma unroll
    for (int j = 0; j < 8; ++j) r[j] = (__bf16)(w0 * (float)a[j] + w1 * (float)c[j]);
    *(bf16x8*)(ob + off) = r;
}

// ---------------- launch ----------------
extern "C" void kernel_launch(void* const* d_in, const int* in_sizes, int n_in,
                              void* d_out, int out_size, void* d_ws, size_t ws_size,
                              hipStream_t stream) {
    const float* x  = (const float*)d_in[0];
    const float* Wq = (const float*)d_in[1];
    const float* bq = (const float*)d_in[2];
    const float* Wk = (const float*)d_in[3];
    const float* bk = (const float*)d_in[4];
    const float* Wv = (const float*)d_in[5];
    const float* bv = (const float*)d_in[6];
    const float* Wo = (const float*)d_in[7];
    const float* bo = (const float*)d_in[8];
    float* out = (float*)d_out;
    char* ws = (char*)d_ws;
    // workspace layout (bytes), total ~50 MB; xb/wtqkv regions reused after GEMM1
    __bf16* xb    = (__bf16*)(ws + 0);          //  8 MB  x bf16 [4096][1024]; later pO0
    __bf16* wtqkv = (__bf16*)(ws + 8388608);    //  6 MB  qkv weights^T; later ml (2 MB)
    __bf16* wot   = (__bf16*)(ws + 14680064);   //  2 MB  W_o^T [1024][1024]
    float*  biasq = (float*) (ws + 16777216);   // 12 KB  fused qkv bias
    __bf16* qb    = (__bf16*)(ws + 16793600);   //  8 MB  q [32][2048][64]
    __bf16* kb    = (__bf16*)(ws + 25182208);   //  8 MB  k [32][2048][64]
    __bf16* vtb   = (__bf16*)(ws + 33570816);   //  8 MB  v^T [32][64][2048]
    __bf16* ob    = (__bf16*)(ws + 41959424);   //  8 MB  attn out [4096][1024]
    __bf16* pO0   = xb;                         //  8 MB  partial O (KV half 0)
    float*  mlbuf = (float*)(ws + 8388608);     //  2 MB  (m,l) per [half][bh][row]

    prep_x_kern<<<4096, 256, 0, stream>>>(x, xb);
    prep_w_kern<<<1024, 256, 0, stream>>>(Wq, Wk, Wv, bq, bk, bv, Wo, wtqkv, biasq, wot);
    gemm_bt<0><<<dim3(24, 32), 256, 0, stream>>>(xb, wtqkv, biasq, qb, kb, vtb, nullptr);
    attn_kern<<<dim3(16, 32), 256, 0, stream>>>(qb, kb, vtb, pO0, ob, mlbuf);
    merge_kern<<<4096, 256, 0, stream>>>(pO0, mlbuf, ob);
    gemm_bt<1><<<dim3(8, 32), 256, 0, stream>>>(ob, wot, bo, nullptr, nullptr, nullptr, out);
}